// Round 10
// baseline (426.374 us; speedup 1.0000x reference)
//
#include <hip/hip_runtime.h>
#include <hip/hip_bf16.h>

typedef __bf16 bf16;
typedef __attribute__((ext_vector_type(8))) __bf16 bf16x8;
typedef __attribute__((ext_vector_type(4))) float f32x4;

static_assert(sizeof(bf16x8) == 16, "bf16x8 must be 16B");

constexpr int N_NODES = 10000;
constexpr int N_EDGES = 320000;
constexpr int KPAD    = 264;   // LDS row stride (bf16): 528B/row -> 2-way bank aliasing (free per m136)

// single-instruction reciprocal (~1 ulp; exact enough under bf16 rounding).
__device__ __forceinline__ float rcp_f(float x) {
  float r; asm("v_rcp_f32 %0, %1" : "=v"(r) : "v"(x)); return r;
}
// silu via rcp: 5 VALU insts vs ~11 for IEEE divide sequence. rcp(inf)=0 -> silu(-big)=0 correct.
__device__ __forceinline__ float silu_f(float x) { return x * rcp_f(1.0f + __expf(-x)); }

// pack two f32 -> (bf16(lo), bf16(hi)) in one u32 via HW packed convert (RNE).
__device__ __forceinline__ unsigned pk_bf16(float lo, float hi) {
  unsigned r;
  asm("v_cvt_pk_bf16_f32 %0, %1, %2" : "=v"(r) : "v"(lo), "v"(hi));
  return r;
}

// ---- transposed-output MFMA with explicit channel-group / edge-offset (edge kernel, 8-wave).
__device__ __forceinline__ void mfmaT_k256e(const bf16* __restrict__ WT, int wstride,
                                            const bf16* Albs, int eoff, int wch, int r, int q,
                                            f32x4 acc[4][4]) {
  for (int k0 = 0; k0 < 256; k0 += 32) {
    bf16x8 a[4], b[4];
#pragma unroll
    for (int mi = 0; mi < 4; ++mi)
      a[mi] = *(const bf16x8*)(WT + (size_t)(wch * 64 + 16 * mi + r) * wstride + k0 + q * 8);
#pragma unroll
    for (int ni = 0; ni < 4; ++ni)
      b[ni] = *(const bf16x8*)(Albs + (eoff + 16 * ni + r) * KPAD + k0 + q * 8);
#pragma unroll
    for (int mi = 0; mi < 4; ++mi)
#pragma unroll
      for (int ni = 0; ni < 4; ++ni)
        acc[mi][ni] = __builtin_amdgcn_mfma_f32_16x16x32_bf16(a[mi], b[ni], acc[mi][ni], 0, 0, 0);
  }
}

// ---- 4x1 variant (16-col tiles: gemm/node splits for TLP)
__device__ __forceinline__ void mfmaT_k256_b1(const bf16* __restrict__ WT, int wstride, int koff,
                                              const bf16* Albs, int w, int r, int q, f32x4 acc[4]) {
  for (int k0 = 0; k0 < 256; k0 += 32) {
    bf16x8 a[4], b;
    b = *(const bf16x8*)(Albs + r * KPAD + k0 + q * 8);
#pragma unroll
    for (int mi = 0; mi < 4; ++mi)
      a[mi] = *(const bf16x8*)(WT + (size_t)(w * 64 + 16 * mi + r) * wstride + koff + k0 + q * 8);
#pragma unroll
    for (int mi = 0; mi < 4; ++mi)
      acc[mi] = __builtin_amdgcn_mfma_f32_16x16x32_bf16(a[mi], b, acc[mi], 0, 0, 0);
  }
}

// ---- prep: consolidated (~2420 blocks); h->bf16 8/thread, coalesced transposes, int4 hist,
// agg zeroing. (UNCHANGED from round 9.)
__device__ __forceinline__ void transpose512(const float* __restrict__ W, bf16* __restrict__ WT,
                                             int local, int tid) {
  int tg = local * 256 + tid;        // 0..16383 covers 256x512
  int j = tg >> 6, k0 = (tg & 63) * 8;
  bf16x8 v;
#pragma unroll
  for (int i = 0; i < 8; ++i) v[i] = (bf16)W[(size_t)(k0 + i) * 256 + j];
  *(bf16x8*)(WT + (size_t)j * 512 + k0) = v;
}
__device__ __forceinline__ void transpose256(const float* __restrict__ W, bf16* __restrict__ WT,
                                             int local, int tid) {
  int tg = local * 256 + tid;        // 0..8191 covers 256x256
  int j = tg >> 5, k0 = (tg & 31) * 8;
  bf16x8 v;
#pragma unroll
  for (int i = 0; i < 8; ++i) v[i] = (bf16)W[(size_t)(k0 + i) * 256 + j];
  *(bf16x8*)(WT + (size_t)j * 256 + k0) = v;
}

__global__ __launch_bounds__(256) void prep_kernel(
    const float* __restrict__ h, const float* __restrict__ We1, const float* __restrict__ We2,
    const float* __restrict__ Wn1, const float* __restrict__ Wn2, const float* __restrict__ Wc1,
    const int* __restrict__ eidx,
    bf16* __restrict__ Hb, bf16* __restrict__ We1T, bf16* __restrict__ Wn1T,
    bf16* __restrict__ We2T, bf16* __restrict__ Wn2T, bf16* __restrict__ Wc1T,
    int* __restrict__ hist, float4* __restrict__ zero_base) {
  int bid = blockIdx.x, tid = threadIdx.x;
  if (bid < 1250) {                  // h -> bf16, 8 elems/thread (vectorized)
    int g = (bid * 256 + tid) * 8;
    float4 u = *(const float4*)(h + g);
    float4 v = *(const float4*)(h + g + 4);
    uint4 o;
    o.x = pk_bf16(u.x, u.y); o.y = pk_bf16(u.z, u.w);
    o.z = pk_bf16(v.x, v.y); o.w = pk_bf16(v.z, v.w);
    *(uint4*)(Hb + g) = o;
    return;
  }
  if (bid < 1474) {                  // 224 transpose blocks
    int wb = bid - 1250;
    if (wb < 64)       transpose512(We1, We1T, wb, tid);
    else if (wb < 128) transpose512(Wn1, Wn1T, wb - 64, tid);
    else if (wb < 160) transpose256(We2, We2T, wb - 128, tid);
    else if (wb < 192) transpose256(Wn2, Wn2T, wb - 160, tid);
    else               transpose256(Wc1, Wc1T, wb - 192, tid);
    return;
  }
  if (bid < 1787) {                  // 313 hist blocks, 4 edges/thread via int4
    int t4 = (bid - 1474) * 256 + tid;
    if (t4 < 80000) {
      int4 e4 = *(const int4*)(eidx + t4 * 4);
      atomicAdd(&hist[e4.x], 1); atomicAdd(&hist[e4.y], 1);
      atomicAdd(&hist[e4.z], 1); atomicAdd(&hist[e4.w], 1);
    }
    return;
  }
  // 633 zero blocks: agg_h + agg_c (647,500 float4), 4 strided float4/thread (coalesced)
  int zb = bid - 1787;
#pragma unroll
  for (int i = 0; i < 4; ++i) {
    int idx = zb * 1024 + i * 256 + tid;
    if (idx < 647500) zero_base[idx] = (float4){0.f, 0.f, 0.f, 0.f};
  }
}

// ---- scan: 1024 threads (10 elems/thread), LDS-staged, writes cursor only. (UNCHANGED.)
__global__ __launch_bounds__(1024) void scan_kernel(const int* __restrict__ hist,
                                                    int* __restrict__ cursor) {
  __shared__ int sh[10000];
  __shared__ int partial[1024];
  int t = threadIdx.x;
  for (int i = 0; i < 10; ++i) { int idx = i * 1024 + t; if (idx < N_NODES) sh[idx] = hist[idx]; }
  __syncthreads();
  int s = 0;
  for (int i = 0; i < 10; ++i) { int idx = t * 10 + i; if (idx < N_NODES) s += sh[idx]; }
  partial[t] = s;
  __syncthreads();
  for (int d = 1; d < 1024; d <<= 1) {
    int v = (t >= d) ? partial[t - d] : 0;
    __syncthreads();
    partial[t] += v;
    __syncthreads();
  }
  int run = partial[t] - s;  // exclusive
  for (int i = 0; i < 10; ++i) {
    int idx = t * 10 + i;
    if (idx < N_NODES) { int hv = sh[idx]; sh[idx] = run; run += hv; }
  }
  __syncthreads();
  for (int i = 0; i < 10; ++i) {
    int idx = i * 1024 + t;
    if (idx < N_NODES) cursor[idx] = sh[idx];
  }
}

// ---- fused scatter + P/Q GEMM. (UNCHANGED from round 9.)
__global__ __launch_bounds__(256, 4) void scatter_gemm(
    const int* __restrict__ eidx, int* __restrict__ cursor, int2* __restrict__ rc,
    const bf16* __restrict__ Hb, const bf16* __restrict__ We1T,
    const float* __restrict__ be1, bf16* __restrict__ P, bf16* __restrict__ Q) {
  int bid = blockIdx.x, tid = threadIdx.x;
  if (bid < 313) {
    int t4 = bid * 256 + tid;
    if (t4 < 80000) {
      int e = t4 * 4;
      int4 r4 = *(const int4*)(eidx + e);
      int4 c4 = *(const int4*)(eidx + N_EDGES + e);
      int p0 = atomicAdd(&cursor[r4.x], 1); rc[p0] = (int2){r4.x, c4.x};
      int p1 = atomicAdd(&cursor[r4.y], 1); rc[p1] = (int2){r4.y, c4.y};
      int p2 = atomicAdd(&cursor[r4.z], 1); rc[p2] = (int2){r4.z, c4.z};
      int p3 = atomicAdd(&cursor[r4.w], 1); rc[p3] = (int2){r4.w, c4.w};
    }
    return;
  }
  int g = bid - 313;
  int w = tid >> 6, lane = tid & 63, r = lane & 15, q = lane >> 4;
  int m0 = (g >> 1) * 16;
  int koff = (g & 1) ? 256 : 0;
  bf16* OUT = (g & 1) ? Q : P;
  bool addb = !(g & 1);
  f32x4 acc[4];
#pragma unroll
  for (int mi = 0; mi < 4; ++mi) acc[mi] = (f32x4){0.f, 0.f, 0.f, 0.f};
  int m = m0 + r;  // max 9999: in range

  for (int k0 = 0; k0 < 256; k0 += 32) {
    bf16x8 a[4], b;
    b = *(const bf16x8*)(Hb + (size_t)m * 256 + k0 + q * 8);
#pragma unroll
    for (int mi = 0; mi < 4; ++mi)
      a[mi] = *(const bf16x8*)(We1T + (size_t)(w * 64 + 16 * mi + r) * 512 + koff + k0 + q * 8);
#pragma unroll
    for (int mi = 0; mi < 4; ++mi)
      acc[mi] = __builtin_amdgcn_mfma_f32_16x16x32_bf16(a[mi], b, acc[mi], 0, 0, 0);
  }
#pragma unroll
  for (int mi = 0; mi < 4; ++mi) {
    int ch = w * 64 + 16 * mi + 4 * q;
    float4 bv = addb ? *(const float4*)(be1 + ch) : (float4){0.f, 0.f, 0.f, 0.f};
    uint2 o;
    o.x = pk_bf16(acc[mi][0] + bv.x, acc[mi][1] + bv.y);
    o.y = pk_bf16(acc[mi][2] + bv.z, acc[mi][3] + bv.w);
    *(uint2*)(OUT + (size_t)m * 256 + ch) = o;
  }
}

// ---- edge kernel: 128 sorted edges/block, 512 threads (8 waves = 4 ch-groups x 2 edge-halves).
// Same per-thread math/register footprint as the 64-edge version (acc[4][4], 64V+64A=128,
// launch_bounds(512,4) allows it) but HALF the barrier crossings and weight A-loads per edge.
// LDS ~73KB -> 2 blocks/CU x 8 waves = 16 waves/CU (same occupancy as before).
__global__ __launch_bounds__(512, 4) void edge_kernel(
    const float* __restrict__ coord, const int2* __restrict__ rc,
    const float* __restrict__ We1,
    const float* __restrict__ be2, const float* __restrict__ bc1,
    const float* __restrict__ Wc2, const float* __restrict__ bc2,
    const bf16* __restrict__ P, const bf16* __restrict__ Q,
    const bf16* __restrict__ We2T, const bf16* __restrict__ Wc1T,
    float* __restrict__ agg_h, float* __restrict__ agg_c) {
  __shared__ __align__(16) bf16 buf[128 * KPAD];
  __shared__ int s_row[128];
  __shared__ float s_rad[128], s_cd[128][3], s_part[128][4], s_scal[128];
  __shared__ int s_rs[129];
  __shared__ int s_nrun;
  __shared__ unsigned long long s_m[2];

  int tid = threadIdx.x;
  int e0 = blockIdx.x * 128;
  int w = tid >> 6, lane = tid & 63, r = lane & 15, q = lane >> 4;
  int wch = w & 3, weh = w >> 2;
  int eoff = weh * 64;

  // --- e1 prefetch state (pre-barrier: addresses from rc registers, no LDS dependency)
  int offv = (tid & 31) * 8;
  int esub = tid >> 5;               // 0..15
  int2 rc0 = rc[e0 + esub];
  bf16x8 pv = *(const bf16x8*)(P + (size_t)rc0.x * 256 + offv);
  bf16x8 qv = *(const bf16x8*)(Q + (size_t)rc0.y * 256 + offv);
  int2 rcn = rc[e0 + 16 + esub];
  float4 wa = *(const float4*)(We1 + 512 * 256 + offv);
  float4 wb = *(const float4*)(We1 + 512 * 256 + offv + 4);

  if (tid < 128) {
    int2 v = rc[e0 + tid];
    int ri = v.x, ci = v.y;
    s_row[tid] = ri;
    float dx = coord[3 * ri + 0] - coord[3 * ci + 0];
    float dy = coord[3 * ri + 1] - coord[3 * ci + 1];
    float dz = coord[3 * ri + 2] - coord[3 * ci + 2];
    s_cd[tid][0] = dx; s_cd[tid][1] = dy; s_cd[tid][2] = dz;
    s_rad[tid] = dx * dx + dy * dy + dz * dz;
  }
  __syncthreads();

  // waves 0-1: per-wave run-boundary ballots (masks published; ranks resolved post-barrier-2)
  if (tid < 128) {
    bool bnd = (tid == 0) || (s_row[tid] != s_row[tid - 1]);
    unsigned long long m = __ballot(bnd);
    if ((tid & 63) == 0) s_m[tid >> 6] = m;
  }

  // e1 = silu(P[row] + Q[col] + radial*We1[512]) -> buf; depth-1 software pipeline.
#pragma unroll
  for (int p = 0; p < 8; ++p) {
    bf16x8 pvc = pv, qvc = qv;
    if (p < 7) {
      pv = *(const bf16x8*)(P + (size_t)rcn.x * 256 + offv);
      qv = *(const bf16x8*)(Q + (size_t)rcn.y * 256 + offv);
    }
    if (p < 6) rcn = rc[e0 + (p + 2) * 16 + esub];
    int e = p * 16 + esub;
    float rad = s_rad[e];
    float f0 = silu_f((float)pvc[0] + (float)qvc[0] + rad * wa.x);
    float f1 = silu_f((float)pvc[1] + (float)qvc[1] + rad * wa.y);
    float f2 = silu_f((float)pvc[2] + (float)qvc[2] + rad * wa.z);
    float f3 = silu_f((float)pvc[3] + (float)qvc[3] + rad * wa.w);
    float f4 = silu_f((float)pvc[4] + (float)qvc[4] + rad * wb.x);
    float f5 = silu_f((float)pvc[5] + (float)qvc[5] + rad * wb.y);
    float f6 = silu_f((float)pvc[6] + (float)qvc[6] + rad * wb.z);
    float f7 = silu_f((float)pvc[7] + (float)qvc[7] + rad * wb.w);
    uint4 o;
    o.x = pk_bf16(f0, f1); o.y = pk_bf16(f2, f3);
    o.z = pk_bf16(f4, f5); o.w = pk_bf16(f6, f7);
    *(uint4*)(buf + e * KPAD + offv) = o;
  }
  __syncthreads();

  // resolve run ranks (waves 0-1; consumed at agg_h after two more barriers)
  if (tid < 128) {
    unsigned long long m0 = s_m[0], m1 = s_m[1];
    int c0 = __popcll(m0);
    bool bnd = (tid == 0) || (s_row[tid] != s_row[tid - 1]);
    unsigned long long mym = (tid < 64) ? m0 : m1;
    int rank = __popcll(mym & ((1ull << (tid & 63)) - 1ull)) + (tid >= 64 ? c0 : 0);
    if (bnd) s_rs[rank] = tid;
    if (tid == 0) { int R = c0 + __popcll(m1); s_nrun = R; s_rs[R] = 128; }
  }

  // GEMM1-T: edge_feat: acc rows = We2 out-channels, cols = edges (wave's 64-edge half)
  {
    f32x4 acc[4][4];
#pragma unroll
    for (int mi = 0; mi < 4; ++mi)
#pragma unroll
      for (int ni = 0; ni < 4; ++ni) acc[mi][ni] = (f32x4){0.f, 0.f, 0.f, 0.f};
    mfmaT_k256e(We2T, 256, buf, eoff, wch, r, q, acc);
    __syncthreads();   // all reads of e1 done before overwrite
#pragma unroll
    for (int mi = 0; mi < 4; ++mi) {
      int ch = wch * 64 + 16 * mi + 4 * q;
      float4 bv = *(const float4*)(be2 + ch);
#pragma unroll
      for (int ni = 0; ni < 4; ++ni) {
        int edge = eoff + 16 * ni + r;
        float f0 = silu_f(acc[mi][ni][0] + bv.x);
        float f1 = silu_f(acc[mi][ni][1] + bv.y);
        float f2 = silu_f(acc[mi][ni][2] + bv.z);
        float f3 = silu_f(acc[mi][ni][3] + bv.w);
        uint2 o; o.x = pk_bf16(f0, f1); o.y = pk_bf16(f2, f3);
        *(uint2*)(buf + edge * KPAD + ch) = o;  // buf[edge][ch], b64 write
      }
    }
  }
  __syncthreads();

  // GEMM2-T k-loop (reads edge_feat) ...
  f32x4 acc2[4][4];
#pragma unroll
  for (int mi = 0; mi < 4; ++mi)
#pragma unroll
    for (int ni = 0; ni < 4; ++ni) acc2[mi][ni] = (f32x4){0.f, 0.f, 0.f, 0.f};
  mfmaT_k256e(Wc1T, 256, buf, eoff, wch, r, q, acc2);

  // ... interleaved with run-based agg_h sums: thread-group g (tid>>8) owns edge half
  // [64g, 64g+64); one atomic per thread per (run ∩ half) — write-combining preserved,
  // straddling runs add <=1 extra atomic per channel per block.
  {
    int R = s_nrun;
    int g = tid >> 8, ch = tid & 255;
    int base = g * 64, top = base + 64;
    for (int rr = 0; rr < R; ++rr) {
      int st = s_rs[rr], en = s_rs[rr + 1];
      int lo = st > base ? st : base;
      int hi = en < top ? en : top;
      if (lo < hi) {
        float s = 0.f;
        for (int e = lo; e < hi; ++e) s += (float)buf[e * KPAD + ch];
        atomicAdd(&agg_h[(size_t)s_row[lo] * 256 + ch], s);
      }
    }
  }

  // GEMM2 fused epilogue: scalar partials p[edge] = sum_ch silu(c1)*Wc2[ch] from registers.
  {
    float p[4] = {0.f, 0.f, 0.f, 0.f};
#pragma unroll
    for (int mi = 0; mi < 4; ++mi) {
      int ch = wch * 64 + 16 * mi + 4 * q;
      float4 bv = *(const float4*)(bc1 + ch);
      float4 wv = *(const float4*)(Wc2 + ch);
#pragma unroll
      for (int ni = 0; ni < 4; ++ni) {
        p[ni] += silu_f(acc2[mi][ni][0] + bv.x) * wv.x
               + silu_f(acc2[mi][ni][1] + bv.y) * wv.y
               + silu_f(acc2[mi][ni][2] + bv.z) * wv.z
               + silu_f(acc2[mi][ni][3] + bv.w) * wv.w;
      }
    }
    // reduce over the 4 q-lane-groups (lanes r, r+16, r+32, r+48 hold the same edge)
#pragma unroll
    for (int ni = 0; ni < 4; ++ni) {
      float v = p[ni];
      v += __shfl_xor(v, 16, 64);
      v += __shfl_xor(v, 32, 64);
      if (q == 0) s_part[eoff + 16 * ni + r][wch] = v;
    }
  }
  __syncthreads();   // s_part ready

  if (tid < 128)
    s_scal[tid] = s_part[tid][0] + s_part[tid][1] + s_part[tid][2] + s_part[tid][3] + bc2[0];
  __syncthreads();

  // coord aggregation: run-based, 6 lanes (xyz x 2 edge-halves), uncontended atomics
  if (tid < 6) {
    int comp = tid % 3, g = tid / 3;
    int base = g * 64, top = base + 64;
    int R = s_nrun;
    for (int rr = 0; rr < R; ++rr) {
      int st = s_rs[rr], en = s_rs[rr + 1];
      int lo = st > base ? st : base;
      int hi = en < top ? en : top;
      if (lo < hi) {
        float s = 0.f;
        for (int e = lo; e < hi; ++e) s += s_cd[e][comp] * s_scal[e];
        atomicAdd(&agg_c[3 * s_row[lo] + comp], s);
      }
    }
  }
}

// ---- node kernel: UNCHANGED from round 9. 16-node tiles (625 blocks).
__global__ __launch_bounds__(256, 2) void node_kernel(
    const bf16* __restrict__ Hb, const float* __restrict__ agg_h,
    const int* __restrict__ hist, const float* __restrict__ coord, const float* __restrict__ agg_c,
    const bf16* __restrict__ Wn1T, const bf16* __restrict__ Wn2T,
    const float* __restrict__ bn1, const float* __restrict__ bn2,
    float* __restrict__ h_out, float* __restrict__ coord_out) {
  __shared__ __align__(16) bf16 buf[16 * KPAD];
  int tid = threadIdx.x, w = tid >> 6, lane = tid & 63, r = lane & 15, q = lane >> 4;
  int m0 = blockIdx.x * 16;
  int m = m0 + r;

  // coord_out
  if (tid < 16) {
    int mm = m0 + tid;
    float c = (float)hist[mm]; if (c < 1.f) c = 1.f;
    coord_out[3 * mm + 0] = coord[3 * mm + 0] + agg_c[3 * mm + 0] / c;
    coord_out[3 * mm + 1] = coord[3 * mm + 1] + agg_c[3 * mm + 1] / c;
    coord_out[3 * mm + 2] = coord[3 * mm + 2] + agg_c[3 * mm + 2] / c;
  }

  // layer1: rows = hidden channels, cols = 16 nodes
  f32x4 acc[4];
#pragma unroll
  for (int mi = 0; mi < 4; ++mi) acc[mi] = (f32x4){0.f, 0.f, 0.f, 0.f};
  for (int k0 = 0; k0 < 256; k0 += 32) {
    bf16x8 a[4], b;
    b = *(const bf16x8*)(Hb + (size_t)m * 256 + k0 + q * 8);
#pragma unroll
    for (int mi = 0; mi < 4; ++mi)
      a[mi] = *(const bf16x8*)(Wn1T + (size_t)(w * 64 + 16 * mi + r) * 512 + k0 + q * 8);
#pragma unroll
    for (int mi = 0; mi < 4; ++mi)
      acc[mi] = __builtin_amdgcn_mfma_f32_16x16x32_bf16(a[mi], b, acc[mi], 0, 0, 0);
  }
  for (int k0 = 0; k0 < 256; k0 += 32) {
    bf16x8 a[4], b;
    {
      const float* ap = agg_h + (size_t)m * 256 + k0 + q * 8;
      float4 u = *(const float4*)ap;
      float4 v = *(const float4*)(ap + 4);
      uint4 o;
      o.x = pk_bf16(u.x, u.y); o.y = pk_bf16(u.z, u.w);
      o.z = pk_bf16(v.x, v.y); o.w = pk_bf16(v.z, v.w);
      b = *(const bf16x8*)&o;
    }
#pragma unroll
    for (int mi = 0; mi < 4; ++mi)
      a[mi] = *(const bf16x8*)(Wn1T + (size_t)(w * 64 + 16 * mi + r) * 512 + 256 + k0 + q * 8);
#pragma unroll
    for (int mi = 0; mi < 4; ++mi)
      acc[mi] = __builtin_amdgcn_mfma_f32_16x16x32_bf16(a[mi], b, acc[mi], 0, 0, 0);
  }
  __syncthreads();
#pragma unroll
  for (int mi = 0; mi < 4; ++mi) {
    int ch = w * 64 + 16 * mi + 4 * q;
    float4 bv = *(const float4*)(bn1 + ch);
    float f0 = silu_f(acc[mi][0] + bv.x);
    float f1 = silu_f(acc[mi][1] + bv.y);
    float f2 = silu_f(acc[mi][2] + bv.z);
    float f3 = silu_f(acc[mi][3] + bv.w);
    uint2 o; o.x = pk_bf16(f0, f1); o.y = pk_bf16(f2, f3);
    *(uint2*)(buf + r * KPAD + ch) = o;
  }
  __syncthreads();
  f32x4 acc2[4];
#pragma unroll
  for (int mi = 0; mi < 4; ++mi) acc2[mi] = (f32x4){0.f, 0.f, 0.f, 0.f};
  mfmaT_k256_b1(Wn2T, 256, 0, buf, w, r, q, acc2);
#pragma unroll
  for (int mi = 0; mi < 4; ++mi) {
    int ch = w * 64 + 16 * mi + 4 * q;
    float4 bv = *(const float4*)(bn2 + ch);
    float4 o;
    o.x = acc2[mi][0] + bv.x;
    o.y = acc2[mi][1] + bv.y;
    o.z = acc2[mi][2] + bv.z;
    o.w = acc2[mi][3] + bv.w;
    *(float4*)(h_out + (size_t)m * 256 + ch) = o;
  }
}

extern "C" void kernel_launch(void* const* d_in, const int* in_sizes, int n_in,
                              void* d_out, int out_size, void* d_ws, size_t ws_size,
                              hipStream_t stream) {
  const float* h     = (const float*)d_in[0];
  const float* coord = (const float*)d_in[1];
  const int*   eidx  = (const int*)d_in[2];
  const float* We1 = (const float*)d_in[3];
  const float* be1 = (const float*)d_in[4];
  const float* We2 = (const float*)d_in[5];
  const float* be2 = (const float*)d_in[6];
  const float* Wn1 = (const float*)d_in[7];
  const float* bn1 = (const float*)d_in[8];
  const float* Wn2 = (const float*)d_in[9];
  const float* bn2 = (const float*)d_in[10];
  const float* Wc1 = (const float*)d_in[11];
  const float* bc1 = (const float*)d_in[12];
  const float* Wc2 = (const float*)d_in[13];
  const float* bc2 = (const float*)d_in[14];

  char* ws = (char*)d_ws;
  float* agg_h = (float*)(ws + 0);          // 10,240,000
  float* agg_c = (float*)(ws + 10240000);   //    120,000
  int*   hist  = (int*)  (ws + 10360000);   //     40,000
  int*   cursor= (int*)  (ws + 10440000);   //     40,000
  int2*  rc    = (int2*) (ws + 10480000);   //  2,560,000
  bf16* Hb   = (bf16*)(ws + 13040000);      //  5,120,000
  bf16* P    = (bf16*)(ws + 18160000);      //  5,120,000
  bf16* Q    = (bf16*)(ws + 23280000);      //  5,120,000
  bf16* We1T = (bf16*)(ws + 28400000);      //    262,144
  bf16* Wn1T = (bf16*)(ws + 28662144);      //    262,144
  bf16* We2T = (bf16*)(ws + 28924288);      //    131,072
  bf16* Wn2T = (bf16*)(ws + 29055360);      //    131,072
  bf16* Wc1T = (bf16*)(ws + 29186432);      //    131,072

  float* h_out = (float*)d_out;
  float* coord_out = h_out + (size_t)N_NODES * 256;

  hipMemsetAsync(hist, 0, 40000, stream);   // hist only; agg zeroing folded into prep
  prep_kernel<<<2420, 256, 0, stream>>>(h, We1, We2, Wn1, Wn2, Wc1, eidx,
                                        Hb, We1T, Wn1T, We2T, Wn2T, Wc1T, hist,
                                        (float4*)agg_h);
  scan_kernel<<<1, 1024, 0, stream>>>(hist, cursor);
  scatter_gemm<<<1563, 256, 0, stream>>>(eidx, cursor, rc, Hb, We1T, be1, P, Q);
  edge_kernel<<<2500, 512, 0, stream>>>(coord, rc, We1, be2, bc1, Wc2, bc2,
                                        P, Q, We2T, Wc1T, agg_h, agg_c);
  node_kernel<<<625, 256, 0, stream>>>(Hb, agg_h, hist, coord, agg_c,
                                       Wn1T, Wn2T, bn1, bn2, h_out, coord_out);
}

// Round 11
// 404.523 us; speedup vs baseline: 1.0540x; 1.0540x over previous
//
#include <hip/hip_runtime.h>
#include <hip/hip_bf16.h>

typedef __bf16 bf16;
typedef __attribute__((ext_vector_type(8))) __bf16 bf16x8;
typedef __attribute__((ext_vector_type(4))) float f32x4;

static_assert(sizeof(bf16x8) == 16, "bf16x8 must be 16B");

constexpr int N_NODES = 10000;
constexpr int N_EDGES = 320000;
constexpr int KPAD    = 264;   // LDS row stride (bf16): 528B/row -> 2-way bank aliasing (free per m136)

// single-instruction reciprocal (~1 ulp; exact enough under bf16 rounding).
__device__ __forceinline__ float rcp_f(float x) {
  float r; asm("v_rcp_f32 %0, %1" : "=v"(r) : "v"(x)); return r;
}
// silu via rcp: 5 VALU insts vs ~11 for IEEE divide sequence. rcp(inf)=0 -> silu(-big)=0 correct.
__device__ __forceinline__ float silu_f(float x) { return x * rcp_f(1.0f + __expf(-x)); }

// pack two f32 -> (bf16(lo), bf16(hi)) in one u32 via HW packed convert (RNE).
__device__ __forceinline__ unsigned pk_bf16(float lo, float hi) {
  unsigned r;
  asm("v_cvt_pk_bf16_f32 %0, %1, %2" : "=v"(r) : "v"(lo), "v"(hi));
  return r;
}

// ---- transposed-output MFMA: acc[mi][ni] = WT-rows x rows-of-Albs (4x4 tile, 64 cols).
// D row(q*4+reg) = out channel (w*64+16*mi+4q+rg), D col(lane&15) = col-row (16*ni+r).
__device__ __forceinline__ void mfmaT_k256(const bf16* __restrict__ WT, int wstride, int koff,
                                           const bf16* Albs, int w, int r, int q, f32x4 acc[4][4]) {
  for (int k0 = 0; k0 < 256; k0 += 32) {
    bf16x8 a[4], b[4];
#pragma unroll
    for (int mi = 0; mi < 4; ++mi)
      a[mi] = *(const bf16x8*)(WT + (size_t)(w * 64 + 16 * mi + r) * wstride + koff + k0 + q * 8);
#pragma unroll
    for (int ni = 0; ni < 4; ++ni)
      b[ni] = *(const bf16x8*)(Albs + (16 * ni + r) * KPAD + k0 + q * 8);
#pragma unroll
    for (int mi = 0; mi < 4; ++mi)
#pragma unroll
      for (int ni = 0; ni < 4; ++ni)
        acc[mi][ni] = __builtin_amdgcn_mfma_f32_16x16x32_bf16(a[mi], b[ni], acc[mi][ni], 0, 0, 0);
  }
}

// ---- 4x1 variant (16-col tiles: gemm/node splits for TLP)
__device__ __forceinline__ void mfmaT_k256_b1(const bf16* __restrict__ WT, int wstride, int koff,
                                              const bf16* Albs, int w, int r, int q, f32x4 acc[4]) {
  for (int k0 = 0; k0 < 256; k0 += 32) {
    bf16x8 a[4], b;
    b = *(const bf16x8*)(Albs + r * KPAD + k0 + q * 8);
#pragma unroll
    for (int mi = 0; mi < 4; ++mi)
      a[mi] = *(const bf16x8*)(WT + (size_t)(w * 64 + 16 * mi + r) * wstride + koff + k0 + q * 8);
#pragma unroll
    for (int mi = 0; mi < 4; ++mi)
      acc[mi] = __builtin_amdgcn_mfma_f32_16x16x32_bf16(a[mi], b, acc[mi], 0, 0, 0);
  }
}

// ---- prep: consolidated (~2420 blocks); h->bf16 8/thread, coalesced transposes, int4 hist,
// agg zeroing.
__device__ __forceinline__ void transpose512(const float* __restrict__ W, bf16* __restrict__ WT,
                                             int local, int tid) {
  int tg = local * 256 + tid;        // 0..16383 covers 256x512
  int j = tg >> 6, k0 = (tg & 63) * 8;
  bf16x8 v;
#pragma unroll
  for (int i = 0; i < 8; ++i) v[i] = (bf16)W[(size_t)(k0 + i) * 256 + j];
  *(bf16x8*)(WT + (size_t)j * 512 + k0) = v;
}
__device__ __forceinline__ void transpose256(const float* __restrict__ W, bf16* __restrict__ WT,
                                             int local, int tid) {
  int tg = local * 256 + tid;        // 0..8191 covers 256x256
  int j = tg >> 5, k0 = (tg & 31) * 8;
  bf16x8 v;
#pragma unroll
  for (int i = 0; i < 8; ++i) v[i] = (bf16)W[(size_t)(k0 + i) * 256 + j];
  *(bf16x8*)(WT + (size_t)j * 256 + k0) = v;
}

__global__ __launch_bounds__(256) void prep_kernel(
    const float* __restrict__ h, const float* __restrict__ We1, const float* __restrict__ We2,
    const float* __restrict__ Wn1, const float* __restrict__ Wn2, const float* __restrict__ Wc1,
    const int* __restrict__ eidx,
    bf16* __restrict__ Hb, bf16* __restrict__ We1T, bf16* __restrict__ Wn1T,
    bf16* __restrict__ We2T, bf16* __restrict__ Wn2T, bf16* __restrict__ Wc1T,
    int* __restrict__ hist, float4* __restrict__ zero_base) {
  int bid = blockIdx.x, tid = threadIdx.x;
  if (bid < 1250) {                  // h -> bf16, 8 elems/thread (vectorized)
    int g = (bid * 256 + tid) * 8;
    float4 u = *(const float4*)(h + g);
    float4 v = *(const float4*)(h + g + 4);
    uint4 o;
    o.x = pk_bf16(u.x, u.y); o.y = pk_bf16(u.z, u.w);
    o.z = pk_bf16(v.x, v.y); o.w = pk_bf16(v.z, v.w);
    *(uint4*)(Hb + g) = o;
    return;
  }
  if (bid < 1474) {                  // 224 transpose blocks
    int wb = bid - 1250;
    if (wb < 64)       transpose512(We1, We1T, wb, tid);
    else if (wb < 128) transpose512(Wn1, Wn1T, wb - 64, tid);
    else if (wb < 160) transpose256(We2, We2T, wb - 128, tid);
    else if (wb < 192) transpose256(Wn2, Wn2T, wb - 160, tid);
    else               transpose256(Wc1, Wc1T, wb - 192, tid);
    return;
  }
  if (bid < 1787) {                  // 313 hist blocks, 4 edges/thread via int4
    int t4 = (bid - 1474) * 256 + tid;
    if (t4 < 80000) {
      int4 e4 = *(const int4*)(eidx + t4 * 4);
      atomicAdd(&hist[e4.x], 1); atomicAdd(&hist[e4.y], 1);
      atomicAdd(&hist[e4.z], 1); atomicAdd(&hist[e4.w], 1);
    }
    return;
  }
  // 633 zero blocks: agg_h + agg_c (647,500 float4), 4 strided float4/thread (coalesced)
  int zb = bid - 1787;
#pragma unroll
  for (int i = 0; i < 4; ++i) {
    int idx = zb * 1024 + i * 256 + tid;
    if (idx < 647500) zero_base[idx] = (float4){0.f, 0.f, 0.f, 0.f};
  }
}

// ---- scan: 1024 threads (10 elems/thread), LDS-staged, writes cursor only.
__global__ __launch_bounds__(1024) void scan_kernel(const int* __restrict__ hist,
                                                    int* __restrict__ cursor) {
  __shared__ int sh[10000];
  __shared__ int partial[1024];
  int t = threadIdx.x;
  for (int i = 0; i < 10; ++i) { int idx = i * 1024 + t; if (idx < N_NODES) sh[idx] = hist[idx]; }
  __syncthreads();
  int s = 0;
  for (int i = 0; i < 10; ++i) { int idx = t * 10 + i; if (idx < N_NODES) s += sh[idx]; }
  partial[t] = s;
  __syncthreads();
  for (int d = 1; d < 1024; d <<= 1) {
    int v = (t >= d) ? partial[t - d] : 0;
    __syncthreads();
    partial[t] += v;
    __syncthreads();
  }
  int run = partial[t] - s;  // exclusive
  for (int i = 0; i < 10; ++i) {
    int idx = t * 10 + i;
    if (idx < N_NODES) { int hv = sh[idx]; sh[idx] = run; run += hv; }
  }
  __syncthreads();
  for (int i = 0; i < 10; ++i) {
    int idx = i * 1024 + t;
    if (idx < N_NODES) cursor[idx] = sh[idx];
  }
}

// ---- fused scatter + P/Q GEMM. blocks 0..312: scatter at 4 edges/thread;
// blocks 313..1562: gemm 16-node tiles.
__global__ __launch_bounds__(256, 4) void scatter_gemm(
    const int* __restrict__ eidx, int* __restrict__ cursor, int2* __restrict__ rc,
    const bf16* __restrict__ Hb, const bf16* __restrict__ We1T,
    const float* __restrict__ be1, bf16* __restrict__ P, bf16* __restrict__ Q) {
  int bid = blockIdx.x, tid = threadIdx.x;
  if (bid < 313) {
    int t4 = bid * 256 + tid;
    if (t4 < 80000) {
      int e = t4 * 4;
      int4 r4 = *(const int4*)(eidx + e);
      int4 c4 = *(const int4*)(eidx + N_EDGES + e);
      int p0 = atomicAdd(&cursor[r4.x], 1); rc[p0] = (int2){r4.x, c4.x};
      int p1 = atomicAdd(&cursor[r4.y], 1); rc[p1] = (int2){r4.y, c4.y};
      int p2 = atomicAdd(&cursor[r4.z], 1); rc[p2] = (int2){r4.z, c4.z};
      int p3 = atomicAdd(&cursor[r4.w], 1); rc[p3] = (int2){r4.w, c4.w};
    }
    return;
  }
  int g = bid - 313;
  int w = tid >> 6, lane = tid & 63, r = lane & 15, q = lane >> 4;
  int m0 = (g >> 1) * 16;
  int koff = (g & 1) ? 256 : 0;
  bf16* OUT = (g & 1) ? Q : P;
  bool addb = !(g & 1);
  f32x4 acc[4];
#pragma unroll
  for (int mi = 0; mi < 4; ++mi) acc[mi] = (f32x4){0.f, 0.f, 0.f, 0.f};
  int m = m0 + r;  // max 9999: in range

  for (int k0 = 0; k0 < 256; k0 += 32) {
    bf16x8 a[4], b;
    b = *(const bf16x8*)(Hb + (size_t)m * 256 + k0 + q * 8);
#pragma unroll
    for (int mi = 0; mi < 4; ++mi)
      a[mi] = *(const bf16x8*)(We1T + (size_t)(w * 64 + 16 * mi + r) * 512 + koff + k0 + q * 8);
#pragma unroll
    for (int mi = 0; mi < 4; ++mi)
      acc[mi] = __builtin_amdgcn_mfma_f32_16x16x32_bf16(a[mi], b, acc[mi], 0, 0, 0);
  }
#pragma unroll
  for (int mi = 0; mi < 4; ++mi) {
    int ch = w * 64 + 16 * mi + 4 * q;
    float4 bv = addb ? *(const float4*)(be1 + ch) : (float4){0.f, 0.f, 0.f, 0.f};
    uint2 o;
    o.x = pk_bf16(acc[mi][0] + bv.x, acc[mi][1] + bv.y);
    o.y = pk_bf16(acc[mi][2] + bv.z, acc[mi][3] + bv.w);
    *(uint2*)(OUT + (size_t)m * 256 + ch) = o;
  }
}

// ---- edge kernel: 64 sorted edges/block, 256 threads, 4 blocks/CU (best-known shape).
// Structural constraint: the 64x256 bf16 LDS exchange tile (32.8KB irreducible) caps
// occupancy at 4 blocks/CU; 512-thread variants failed twice (regs r1, block-quant r10).
__global__ __launch_bounds__(256, 4) void edge_kernel(
    const float* __restrict__ coord, const int2* __restrict__ rc,
    const float* __restrict__ We1,
    const float* __restrict__ be2, const float* __restrict__ bc1,
    const float* __restrict__ Wc2, const float* __restrict__ bc2,
    const bf16* __restrict__ P, const bf16* __restrict__ Q,
    const bf16* __restrict__ We2T, const bf16* __restrict__ Wc1T,
    float* __restrict__ agg_h, float* __restrict__ agg_c) {
  __shared__ __align__(16) bf16 buf[64 * KPAD];
  __shared__ int s_row[64];
  __shared__ float s_rad[64], s_cd[64][3], s_part[64][4], s_scal[64];
  __shared__ int s_rs[65];
  __shared__ int s_nrun;

  int tid = threadIdx.x;
  int e0 = blockIdx.x * 64;
  int w = tid >> 6, lane = tid & 63, r = lane & 15, q = lane >> 4;

  // --- e1 prefetch state (pre-barrier: addresses from rc registers, no LDS dependency)
  int offv = (tid & 31) * 8;
  int esub = tid >> 5;
  int2 rc0 = rc[e0 + esub];
  bf16x8 pv = *(const bf16x8*)(P + (size_t)rc0.x * 256 + offv);
  bf16x8 qv = *(const bf16x8*)(Q + (size_t)rc0.y * 256 + offv);
  int2 rcn = rc[e0 + 8 + esub];
  float4 wa = *(const float4*)(We1 + 512 * 256 + offv);
  float4 wb = *(const float4*)(We1 + 512 * 256 + offv + 4);

  if (tid < 64) {
    int2 v = rc[e0 + tid];
    int ri = v.x, ci = v.y;
    s_row[tid] = ri;
    float dx = coord[3 * ri + 0] - coord[3 * ci + 0];
    float dy = coord[3 * ri + 1] - coord[3 * ci + 1];
    float dz = coord[3 * ri + 2] - coord[3 * ci + 2];
    s_cd[tid][0] = dx; s_cd[tid][1] = dy; s_cd[tid][2] = dz;
    s_rad[tid] = dx * dx + dy * dy + dz * dz;
  }
  __syncthreads();

  // wave 0: run boundaries of sorted rows (avg 2-3 runs/block)
  if (tid < 64) {
    bool bnd = (tid == 0) || (s_row[tid] != s_row[tid - 1]);
    unsigned long long m = __ballot(bnd);
    int rank = __popcll(m & ((1ull << tid) - 1ull));
    if (bnd) s_rs[rank] = tid;
    if (tid == 0) { int R = __popcll(m); s_nrun = R; s_rs[R] = 64; }
  }

  // e1 = silu(P[row] + Q[col] + radial*We1[512]) -> buf; depth-1 software pipeline.
#pragma unroll
  for (int p = 0; p < 8; ++p) {
    bf16x8 pvc = pv, qvc = qv;
    if (p < 7) {
      pv = *(const bf16x8*)(P + (size_t)rcn.x * 256 + offv);
      qv = *(const bf16x8*)(Q + (size_t)rcn.y * 256 + offv);
    }
    if (p < 6) rcn = rc[e0 + (p + 2) * 8 + esub];
    int e = p * 8 + esub;
    float rad = s_rad[e];
    float f0 = silu_f((float)pvc[0] + (float)qvc[0] + rad * wa.x);
    float f1 = silu_f((float)pvc[1] + (float)qvc[1] + rad * wa.y);
    float f2 = silu_f((float)pvc[2] + (float)qvc[2] + rad * wa.z);
    float f3 = silu_f((float)pvc[3] + (float)qvc[3] + rad * wa.w);
    float f4 = silu_f((float)pvc[4] + (float)qvc[4] + rad * wb.x);
    float f5 = silu_f((float)pvc[5] + (float)qvc[5] + rad * wb.y);
    float f6 = silu_f((float)pvc[6] + (float)qvc[6] + rad * wb.z);
    float f7 = silu_f((float)pvc[7] + (float)qvc[7] + rad * wb.w);
    uint4 o;
    o.x = pk_bf16(f0, f1); o.y = pk_bf16(f2, f3);
    o.z = pk_bf16(f4, f5); o.w = pk_bf16(f6, f7);
    *(uint4*)(buf + e * KPAD + offv) = o;
  }
  __syncthreads();

  // GEMM1-T: edge_feat: acc rows = We2 out-channels, cols = edges
  {
    f32x4 acc[4][4];
#pragma unroll
    for (int mi = 0; mi < 4; ++mi)
#pragma unroll
      for (int ni = 0; ni < 4; ++ni) acc[mi][ni] = (f32x4){0.f, 0.f, 0.f, 0.f};
    mfmaT_k256(We2T, 256, 0, buf, w, r, q, acc);
    __syncthreads();   // all reads of e1 done before overwrite
#pragma unroll
    for (int mi = 0; mi < 4; ++mi) {
      int ch = w * 64 + 16 * mi + 4 * q;
      float4 bv = *(const float4*)(be2 + ch);
#pragma unroll
      for (int ni = 0; ni < 4; ++ni) {
        int edge = 16 * ni + r;
        float f0 = silu_f(acc[mi][ni][0] + bv.x);
        float f1 = silu_f(acc[mi][ni][1] + bv.y);
        float f2 = silu_f(acc[mi][ni][2] + bv.z);
        float f3 = silu_f(acc[mi][ni][3] + bv.w);
        uint2 o; o.x = pk_bf16(f0, f1); o.y = pk_bf16(f2, f3);
        *(uint2*)(buf + edge * KPAD + ch) = o;  // buf[edge][ch], b64 write
      }
    }
  }
  __syncthreads();

  // GEMM2-T k-loop (reads edge_feat) ...
  f32x4 acc2[4][4];
#pragma unroll
  for (int mi = 0; mi < 4; ++mi)
#pragma unroll
    for (int ni = 0; ni < 4; ++ni) acc2[mi][ni] = (f32x4){0.f, 0.f, 0.f, 0.f};
  mfmaT_k256(Wc1T, 256, 0, buf, w, r, q, acc2);

  // ... interleaved with run-based agg_h column sums (one atomic per thread per run:
  // L2 write-combines the 256-channel row into few lines; WRITE_SIZE stays ~15 MB)
  {
    int R = s_nrun;
    for (int rr = 0; rr < R; ++rr) {
      int st = s_rs[rr], en = s_rs[rr + 1];
      float s = 0.f;
      for (int e = st; e < en; ++e) s += (float)buf[e * KPAD + tid];
      atomicAdd(&agg_h[(size_t)s_row[st] * 256 + tid], s);
    }
  }

  // GEMM2 fused epilogue: scalar partials p[edge] = sum_ch silu(c1)*Wc2[ch],
  // computed straight from acc2 registers (c1 never written to LDS).
  {
    float p[4] = {0.f, 0.f, 0.f, 0.f};
#pragma unroll
    for (int mi = 0; mi < 4; ++mi) {
      int ch = w * 64 + 16 * mi + 4 * q;
      float4 bv = *(const float4*)(bc1 + ch);
      float4 wv = *(const float4*)(Wc2 + ch);
#pragma unroll
      for (int ni = 0; ni < 4; ++ni) {
        p[ni] += silu_f(acc2[mi][ni][0] + bv.x) * wv.x
               + silu_f(acc2[mi][ni][1] + bv.y) * wv.y
               + silu_f(acc2[mi][ni][2] + bv.z) * wv.z
               + silu_f(acc2[mi][ni][3] + bv.w) * wv.w;
      }
    }
    // reduce over the 4 q-lane-groups (lanes r, r+16, r+32, r+48 hold the same edge)
#pragma unroll
    for (int ni = 0; ni < 4; ++ni) {
      float v = p[ni];
      v += __shfl_xor(v, 16, 64);
      v += __shfl_xor(v, 32, 64);
      if (q == 0) s_part[16 * ni + r][w] = v;
    }
  }
  __syncthreads();   // s_part ready

  if (tid < 64)
    s_scal[tid] = s_part[tid][0] + s_part[tid][1] + s_part[tid][2] + s_part[tid][3] + bc2[0];
  __syncthreads();

  // coord aggregation: run-based, one lane per xyz component (few, uncontended atomics)
  if (tid < 3) {
    int R = s_nrun;
    for (int rr = 0; rr < R; ++rr) {
      int st = s_rs[rr], en = s_rs[rr + 1];
      float s = 0.f;
      for (int e = st; e < en; ++e) s += s_cd[e][tid] * s_scal[e];
      atomicAdd(&agg_c[3 * s_row[st] + tid], s);
    }
  }
}

// ---- node kernel: 16-node tiles (625 blocks); fused coord_out + agg->bf16 + 2-layer MLP.
__global__ __launch_bounds__(256, 2) void node_kernel(
    const bf16* __restrict__ Hb, const float* __restrict__ agg_h,
    const int* __restrict__ hist, const float* __restrict__ coord, const float* __restrict__ agg_c,
    const bf16* __restrict__ Wn1T, const bf16* __restrict__ Wn2T,
    const float* __restrict__ bn1, const float* __restrict__ bn2,
    float* __restrict__ h_out, float* __restrict__ coord_out) {
  __shared__ __align__(16) bf16 buf[16 * KPAD];
  int tid = threadIdx.x, w = tid >> 6, lane = tid & 63, r = lane & 15, q = lane >> 4;
  int m0 = blockIdx.x * 16;
  int m = m0 + r;

  // coord_out
  if (tid < 16) {
    int mm = m0 + tid;
    float c = (float)hist[mm]; if (c < 1.f) c = 1.f;
    coord_out[3 * mm + 0] = coord[3 * mm + 0] + agg_c[3 * mm + 0] / c;
    coord_out[3 * mm + 1] = coord[3 * mm + 1] + agg_c[3 * mm + 1] / c;
    coord_out[3 * mm + 2] = coord[3 * mm + 2] + agg_c[3 * mm + 2] / c;
  }

  // layer1: rows = hidden channels, cols = 16 nodes
  f32x4 acc[4];
#pragma unroll
  for (int mi = 0; mi < 4; ++mi) acc[mi] = (f32x4){0.f, 0.f, 0.f, 0.f};
  for (int k0 = 0; k0 < 256; k0 += 32) {
    bf16x8 a[4], b;
    b = *(const bf16x8*)(Hb + (size_t)m * 256 + k0 + q * 8);
#pragma unroll
    for (int mi = 0; mi < 4; ++mi)
      a[mi] = *(const bf16x8*)(Wn1T + (size_t)(w * 64 + 16 * mi + r) * 512 + k0 + q * 8);
#pragma unroll
    for (int mi = 0; mi < 4; ++mi)
      acc[mi] = __builtin_amdgcn_mfma_f32_16x16x32_bf16(a[mi], b, acc[mi], 0, 0, 0);
  }
  for (int k0 = 0; k0 < 256; k0 += 32) {
    bf16x8 a[4], b;
    {
      const float* ap = agg_h + (size_t)m * 256 + k0 + q * 8;
      float4 u = *(const float4*)ap;
      float4 v = *(const float4*)(ap + 4);
      uint4 o;
      o.x = pk_bf16(u.x, u.y); o.y = pk_bf16(u.z, u.w);
      o.z = pk_bf16(v.x, v.y); o.w = pk_bf16(v.z, v.w);
      b = *(const bf16x8*)&o;
    }
#pragma unroll
    for (int mi = 0; mi < 4; ++mi)
      a[mi] = *(const bf16x8*)(Wn1T + (size_t)(w * 64 + 16 * mi + r) * 512 + 256 + k0 + q * 8);
#pragma unroll
    for (int mi = 0; mi < 4; ++mi)
      acc[mi] = __builtin_amdgcn_mfma_f32_16x16x32_bf16(a[mi], b, acc[mi], 0, 0, 0);
  }
  __syncthreads();
#pragma unroll
  for (int mi = 0; mi < 4; ++mi) {
    int ch = w * 64 + 16 * mi + 4 * q;
    float4 bv = *(const float4*)(bn1 + ch);
    float f0 = silu_f(acc[mi][0] + bv.x);
    float f1 = silu_f(acc[mi][1] + bv.y);
    float f2 = silu_f(acc[mi][2] + bv.z);
    float f3 = silu_f(acc[mi][3] + bv.w);
    uint2 o; o.x = pk_bf16(f0, f1); o.y = pk_bf16(f2, f3);
    *(uint2*)(buf + r * KPAD + ch) = o;
  }
  __syncthreads();
  f32x4 acc2[4];
#pragma unroll
  for (int mi = 0; mi < 4; ++mi) acc2[mi] = (f32x4){0.f, 0.f, 0.f, 0.f};
  mfmaT_k256_b1(Wn2T, 256, 0, buf, w, r, q, acc2);
#pragma unroll
  for (int mi = 0; mi < 4; ++mi) {
    int ch = w * 64 + 16 * mi + 4 * q;
    float4 bv = *(const float4*)(bn2 + ch);
    float4 o;
    o.x = acc2[mi][0] + bv.x;
    o.y = acc2[mi][1] + bv.y;
    o.z = acc2[mi][2] + bv.z;
    o.w = acc2[mi][3] + bv.w;
    *(float4*)(h_out + (size_t)m * 256 + ch) = o;
  }
}

extern "C" void kernel_launch(void* const* d_in, const int* in_sizes, int n_in,
                              void* d_out, int out_size, void* d_ws, size_t ws_size,
                              hipStream_t stream) {
  const float* h     = (const float*)d_in[0];
  const float* coord = (const float*)d_in[1];
  const int*   eidx  = (const int*)d_in[2];
  const float* We1 = (const float*)d_in[3];
  const float* be1 = (const float*)d_in[4];
  const float* We2 = (const float*)d_in[5];
  const float* be2 = (const float*)d_in[6];
  const float* Wn1 = (const float*)d_in[7];
  const float* bn1 = (const float*)d_in[8];
  const float* Wn2 = (const float*)d_in[9];
  const float* bn2 = (const float*)d_in[10];
  const float* Wc1 = (const float*)d_in[11];
  const float* bc1 = (const float*)d_in[12];
  const float* Wc2 = (const float*)d_in[13];
  const float* bc2 = (const float*)d_in[14];

  char* ws = (char*)d_ws;
  float* agg_h = (float*)(ws + 0);          // 10,240,000
  float* agg_c = (float*)(ws + 10240000);   //    120,000
  int*   hist  = (int*)  (ws + 10360000);   //     40,000
  int*   cursor= (int*)  (ws + 10440000);   //     40,000
  int2*  rc    = (int2*) (ws + 10480000);   //  2,560,000
  bf16* Hb   = (bf16*)(ws + 13040000);      //  5,120,000
  bf16* P    = (bf16*)(ws + 18160000);      //  5,120,000
  bf16* Q    = (bf16*)(ws + 23280000);      //  5,120,000
  bf16* We1T = (bf16*)(ws + 28400000);      //    262,144
  bf16* Wn1T = (bf16*)(ws + 28662144);      //    262,144
  bf16* We2T = (bf16*)(ws + 28924288);      //    131,072
  bf16* Wn2T = (bf16*)(ws + 29055360);      //    131,072
  bf16* Wc1T = (bf16*)(ws + 29186432);      //    131,072

  float* h_out = (float*)d_out;
  float* coord_out = h_out + (size_t)N_NODES * 256;

  hipMemsetAsync(hist, 0, 40000, stream);   // hist only; agg zeroing folded into prep
  prep_kernel<<<2420, 256, 0, stream>>>(h, We1, We2, Wn1, Wn2, Wc1, eidx,
                                        Hb, We1T, Wn1T, We2T, Wn2T, Wc1T, hist,
                                        (float4*)agg_h);
  scan_kernel<<<1, 1024, 0, stream>>>(hist, cursor);
  scatter_gemm<<<1563, 256, 0, stream>>>(eidx, cursor, rc, Hb, We1T, be1, P, Q);
  edge_kernel<<<5000, 256, 0, stream>>>(coord, rc, We1, be2, bc1, Wc2, bc2,
                                        P, Q, We2T, Wc1T, agg_h, agg_c);
  node_kernel<<<625, 256, 0, stream>>>(Hb, agg_h, hist, coord, agg_c,
                                       Wn1T, Wn2T, bn1, bn2, h_out, coord_out);
}